// Round 3
// baseline (1138.043 us; speedup 1.0000x reference)
//
#include <hip/hip_runtime.h>
#include <hip/hip_cooperative_groups.h>
#include <math.h>

namespace cg = cooperative_groups;

#define HSTEP 0.1f
#define EPS_IN 1e-5f
#define BIGF 1e10f
#define DCF 3.79f

// ---------------------------------------------------------------------------
// One cooperative kernel for the entire pipeline.
// 256 blocks x 512 threads; block g: b = g>>5 (batch), c = g&31 (channel lane).
// Stage widths: 2048 -> T=512 thr/row (4 pos each), P=1 parallel row;
//               1024 -> T=256, P=2 parallel rows.
// ---------------------------------------------------------------------------

// generic conv stage: optionally transposed weights, optional instance-norm+
// relu(+skip) (CIR) or xc -= HSTEP*conv*m (AXPY), optional fused avg-pool,
// optional fused upsample-on-read.
template<bool UPS, bool AXPY>
__device__ void conv_stage(const float* __restrict__ in_b, float* __restrict__ out_b,
                           const float* __restrict__ Kw, bool TR,
                           int Cin, int Cout, int Ns,
                           const float* __restrict__ mlds, float den,
                           const float* __restrict__ skip_b,
                           float* __restrict__ pool_b, const float* __restrict__ mhalf,
                           int c, int tid,
                           float* s_wt, float* s_red, float* s_row)
{
    const int T    = Ns >> 2;                 // threads per row
    const int P    = (T == 512) ? 1 : 2;      // parallel rows
    const int iters = (Cout >> 5) / P;
    const int grp  = (P == 2) ? (tid >> 8) : 0;
    const int tsub = (P == 2) ? (tid & 255) : tid;
    float* swt = s_wt + grp * 384;
    const int srcw = UPS ? (Ns >> 1) : Ns;

    for (int it = 0; it < iters; ++it) {
        const int co = c + 32 * (grp + P * it);
        for (int i = tsub; i < Cin * 3; i += T) {
            int ci = i / 3, k = i % 3;
            swt[i] = TR ? Kw[((size_t)ci * Cout + co) * 3 + (2 - k)]
                        : Kw[((size_t)co * Cin + ci) * 3 + k];
        }
        __syncthreads();

        const int n0 = tsub * 4;
        float a0 = 0.f, a1 = 0.f, a2 = 0.f, a3 = 0.f;
        #pragma unroll 4
        for (int ci = 0; ci < Cin; ++ci) {
            const float* src = in_b + (size_t)ci * srcw;
            float xl, x0, x1, x2, x3, xr;
            if (!UPS) {
                const float4 v = *(const float4*)(src + n0);
                x0 = v.x; x1 = v.y; x2 = v.z; x3 = v.w;
                xl = (n0 > 0)      ? src[n0 - 1] : 0.f;
                xr = (n0 + 4 < Ns) ? src[n0 + 4] : 0.f;
            } else {
                const float2 s = *(const float2*)(src + (n0 >> 1));
                x0 = s.x * mlds[n0];     x1 = s.x * mlds[n0 + 1];
                x2 = s.y * mlds[n0 + 2]; x3 = s.y * mlds[n0 + 3];
                xl = (n0 > 0)      ? src[(n0 - 1) >> 1] * mlds[n0 - 1] : 0.f;
                xr = (n0 + 4 < Ns) ? src[(n0 + 4) >> 1] * mlds[n0 + 4] : 0.f;
            }
            const float w0 = swt[ci * 3], w1 = swt[ci * 3 + 1], w2 = swt[ci * 3 + 2];
            a0 = fmaf(w0, xl, fmaf(w1, x0, fmaf(w2, x1, a0)));
            a1 = fmaf(w0, x0, fmaf(w1, x1, fmaf(w2, x2, a1)));
            a2 = fmaf(w0, x1, fmaf(w1, x2, fmaf(w2, x3, a2)));
            a3 = fmaf(w0, x2, fmaf(w1, x3, fmaf(w2, xr, a3)));
        }
        const float m0 = mlds[n0], m1 = mlds[n0 + 1], m2 = mlds[n0 + 2], m3 = mlds[n0 + 3];
        float v0 = a0 * m0, v1 = a1 * m1, v2 = a2 * m2, v3 = a3 * m3;
        float* orow = out_b ? out_b + (size_t)co * Ns + n0 : nullptr;

        if constexpr (AXPY) {
            float4 cur = *(const float4*)orow;
            float4 rr;
            rr.x = cur.x - HSTEP * v0; rr.y = cur.y - HSTEP * v1;
            rr.z = cur.z - HSTEP * v2; rr.w = cur.w - HSTEP * v3;
            *(float4*)orow = rr;
        } else {
            float ls = v0 + v1 + v2 + v3;
            float lq = v0 * v0 + v1 * v1 + v2 * v2 + v3 * v3;
            #pragma unroll
            for (int off = 32; off > 0; off >>= 1) {
                ls += __shfl_down(ls, off);
                lq += __shfl_down(lq, off);
            }
            const int wig = tsub >> 6;
            const int wpg = T >> 6;
            if ((tsub & 63) == 0) { s_red[grp * 16 + wig * 2] = ls; s_red[grp * 16 + wig * 2 + 1] = lq; }
            __syncthreads();
            float ts = 0.f, tq = 0.f;
            for (int i2 = 0; i2 < wpg; ++i2) { ts += s_red[grp * 16 + i2 * 2]; tq += s_red[grp * 16 + i2 * 2 + 1]; }
            const float mean = ts / den;
            const float inv  = 1.f / sqrtf(tq / den - mean * mean + EPS_IN);
            float r0 = fmaxf((v0 - mean * m0) * inv, 0.f);
            float r1 = fmaxf((v1 - mean * m1) * inv, 0.f);
            float r2 = fmaxf((v2 - mean * m2) * inv, 0.f);
            float r3 = fmaxf((v3 - mean * m3) * inv, 0.f);
            if (skip_b) {
                const float4 sk = *(const float4*)(skip_b + (size_t)co * Ns + n0);
                r0 += sk.x; r1 += sk.y; r2 += sk.z; r3 += sk.w;
            }
            if (orow) {
                float4 rr; rr.x = r0; rr.y = r1; rr.z = r2; rr.w = r3;
                *(float4*)orow = rr;
            }
            if (pool_b) {
                float* srow = s_row + grp * 2048;
                srow[n0] = r0; srow[n0 + 1] = r1; srow[n0 + 2] = r2; srow[n0 + 3] = r3;
                __syncthreads();
                const int Nh = Ns >> 1;
                if (tsub < (T >> 1)) {
                    const int np0 = tsub * 4;
                    float zm1 = (np0 > 0) ? srow[2 * np0 - 1] : 0.f;
                    float4 p;
                    p.x = (zm1 + srow[2*np0] + srow[2*np0+1]) * (1.f/3.f) * mhalf[np0];
                    p.y = (srow[2*np0+1] + srow[2*np0+2] + srow[2*np0+3]) * (1.f/3.f) * mhalf[np0+1];
                    p.z = (srow[2*np0+3] + srow[2*np0+4] + srow[2*np0+5]) * (1.f/3.f) * mhalf[np0+2];
                    p.w = (srow[2*np0+5] + srow[2*np0+6] + srow[2*np0+7]) * (1.f/3.f) * mhalf[np0+3];
                    *(float4*)(pool_b + (size_t)co * Nh + np0) = p;
                }
            }
        }
        __syncthreads();
    }
}

// dist_constraint stage (port of the round-2-verified dc_all, 512 threads)
__device__ void dc_stage(const float* __restrict__ xc32, const float* __restrict__ x,
                         const float* __restrict__ Wg, float* __restrict__ xout,
                         int b, int tid, const float* sm_mask, float den0,
                         float* ub, unsigned long long* smk, float* sW)
{
    const int N = 2048;
    float* sX0 = ub;         float* sX1 = ub + 2048;  float* sX2 = ub + 4096;
    float* sD0 = ub + 6144;  float* sD1 = ub + 8192;  float* sD2 = ub + 10240;
    if (tid < 96) sW[tid] = Wg[tid];
    __syncthreads();
    const float* flagrow = x + ((size_t)b * 24 + 23) * N;
    const float* cxr = x + ((size_t)b * 24 + 20) * N;
    const float* cyr = x + ((size_t)b * 24 + 21) * N;
    const float* czr = x + ((size_t)b * 24 + 22) * N;

    #pragma unroll
    for (int r = 0; r < 4; ++r) {
        int n = tid + r * 512;
        float mk = sm_mask[n];
        float fl = flagrow[n];
        float v0 = 0.f, v1 = 0.f, v2 = 0.f;
        #pragma unroll 8
        for (int ci = 0; ci < 32; ++ci) {
            float xv = xc32[(size_t)ci * N + n];
            v0 = fmaf(sW[ci], xv, v0);
            v1 = fmaf(sW[32 + ci], xv, v1);
            v2 = fmaf(sW[64 + ci], xv, v2);
        }
        v0 *= mk; v1 *= mk; v2 *= mk;
        bool fixed = (fl == 1.f);
        if (fixed) { v0 = cxr[n]; v1 = cyr[n]; v2 = czr[n]; }
        sX0[n] = v0; sX1[n] = v1; sX2[n] = v2;
        unsigned long long bm = __ballot(fixed);
        if ((tid & 63) == 0) smk[n >> 6] = bm;
    }
    __syncthreads();

    #pragma unroll
    for (int r = 0; r < 4; ++r) {
        int n = tid + r * 512;
        if (n < N - 1) {
            float d0 = sX0[n+1] - sX0[n], d1 = sX1[n+1] - sX1[n], d2 = sX2[n+1] - sX2[n];
            float d  = d0 * d0 + d1 * d1 + d2 * d2;
            bool avM = floorf((sm_mask[n] + sm_mask[n + 1]) * 0.5f) < 0.5f;
            if (avM) { sD0[n] = 0.f; sD1[n] = 0.f; sD2[n] = 0.f; }
            else {
                float sq = sqrtf(d);
                sD0[n] = (d0 / sq) * DCF; sD1[n] = (d1 / sq) * DCF; sD2[n] = (d2 / sq) * DCF;
            }
        }
    }
    __syncthreads();

    int len = (int)den0;
    #pragma unroll
    for (int r = 0; r < 4; ++r) {
        int j  = tid + r * 512;
        int cc = j >> 6, jl = j & 63;

        unsigned long long below = smk[cc] & (~0ull >> (63 - jl));
        int p = -1;
        if (below) p = (cc << 6) + 63 - __clzll(below);
        else {
            for (int c2 = cc - 1; c2 >= 0; --c2) {
                unsigned long long m = smk[c2];
                if (m) { p = (c2 << 6) + 63 - __clzll(m); break; }
            }
        }
        float l0, l1, l2, wl;
        if (p >= 0) {
            wl = (float)(j - p);
            l0 = sX0[p]; l1 = sX1[p]; l2 = sX2[p];
            int kend = min(j, len - 1);
            for (int k = p; k < kend; ++k) { l0 += sD0[k]; l1 += sD1[k]; l2 += sD2[k]; }
        } else { wl = BIGF; l0 = sX0[j]; l1 = sX1[j]; l2 = sX2[j]; }

        unsigned long long above = smk[cc] & (~0ull << jl);
        int q = -1;
        if (above) q = (cc << 6) + __ffsll(above) - 1;
        else {
            for (int c2 = cc + 1; c2 < 32; ++c2) {
                unsigned long long m = smk[c2];
                if (m) { q = (c2 << 6) + __ffsll(m) - 1; break; }
            }
        }
        float r0, r1, r2, wr;
        if (q >= 0) {
            wr = (float)(q - j);
            r0 = sX0[q]; r1 = sX1[q]; r2 = sX2[q];
            for (int k = q - 1; k >= j; --k) { r0 -= sD0[k]; r1 -= sD1[k]; r2 -= sD2[k]; }
        } else { wr = BIGF; r0 = sX0[j]; r1 = sX1[j]; r2 = sX2[j]; }

        float ws_ = wl + wr, cl, cr;
        if (ws_ == 0.f) { cl = 0.5f; cr = 0.5f; }
        else            { cl = wr / ws_; cr = wl / ws_; }
        float mk = sm_mask[j];
        xout[j]         = (l0 * cl + r0 * cr) * mk;
        xout[N + j]     = (l1 * cl + r1 * cr) * mk;
        xout[2 * N + j] = (l2 * cl + r2 * cr) * mk;
    }
}

__global__ void __launch_bounds__(512, 1)
vnet_all(const float* __restrict__ x, const float* __restrict__ mask,
         const float* __restrict__ K0, const float* __restrict__ K1,
         const float* __restrict__ K2, const float* __restrict__ K3,
         const float* __restrict__ K4, const float* __restrict__ K5,
         const float* __restrict__ K6, const float* __restrict__ W,
         float* __restrict__ out, float* __restrict__ B0, float* __restrict__ B1,
         float* __restrict__ B2, float* __restrict__ B3)
{
    __shared__ __align__(16) float sm_mask[2048];
    __shared__ __align__(16) float sm_M1[1024];
    __shared__ __align__(16) float sm_M2[512];
    __shared__ float s_wt[2 * 384];
    __shared__ float s_red[32];
    __shared__ __align__(16) float s_row[2 * 2048];
    __shared__ float s_den[2];
    __shared__ __align__(16) float ubig[12288];
    __shared__ unsigned long long smk[32];
    __shared__ float sWl[96];

    cg::grid_group grid = cg::this_grid();
    const int g = blockIdx.x, tid = threadIdx.x;
    const int b = g >> 5, c = g & 31;

    // ---- per-block mask prep (redundant per batch; no grid sync needed) ----
    {
        const float* mrow = mask + (size_t)b * 2048;
        *(float4*)(sm_mask + tid * 4) = *(const float4*)(mrow + tid * 4);
        __syncthreads();
        if (tid < 256) {
            int np0 = tid * 4;
            #pragma unroll
            for (int k = 0; k < 4; ++k) {
                int np = np0 + k;
                float s = sm_mask[2 * np];
                if (2 * np - 1 >= 0)   s += sm_mask[2 * np - 1];
                if (2 * np + 1 < 2048) s += sm_mask[2 * np + 1];
                sm_M1[np] = (s * (1.f / 3.f) >= 0.5f) ? 1.f : 0.f;
            }
        }
        __syncthreads();
        if (tid < 128) {
            int np0 = tid * 4;
            #pragma unroll
            for (int k = 0; k < 4; ++k) {
                int np = np0 + k;
                float s = sm_M1[2 * np];
                if (2 * np - 1 >= 0)   s += sm_M1[2 * np - 1];
                if (2 * np + 1 < 1024) s += sm_M1[2 * np + 1];
                sm_M2[np] = (s * (1.f / 3.f) >= 0.5f) ? 1.f : 0.f;
            }
        }
        __syncthreads();
        float l0 = sm_mask[tid*4] + sm_mask[tid*4+1] + sm_mask[tid*4+2] + sm_mask[tid*4+3];
        float l1 = sm_M1[tid * 2] + sm_M1[tid * 2 + 1];
        #pragma unroll
        for (int off = 32; off > 0; off >>= 1) { l0 += __shfl_down(l0, off); l1 += __shfl_down(l1, off); }
        if ((tid & 63) == 0) { s_red[(tid >> 6) * 2] = l0; s_red[(tid >> 6) * 2 + 1] = l1; }
        __syncthreads();
        if (tid == 0) {
            float t0 = 0.f, t1 = 0.f;
            for (int i = 0; i < 8; ++i) { t0 += s_red[i * 2]; t1 += s_red[i * 2 + 1]; }
            s_den[0] = t0; s_den[1] = t1;
        }
        __syncthreads();
    }
    const float den0 = s_den[0], den1 = s_den[1];

    const size_t S = 65536;   // per-batch slab (32x2048 = 64x1024 = 128x512)
    const float* xb = x + (size_t)b * 24 * 2048;
    float* p0 = B0 + (size_t)b * S;
    float* p1 = B1 + (size_t)b * S;
    float* p2 = B2 + (size_t)b * S;
    float* p3 = B3 + (size_t)b * S;

    #define GS() grid.sync()

    // down path
    conv_stage<false,false>(xb, p0, K0, false, 24, 32, 2048, sm_mask, den0, nullptr, nullptr, nullptr, c, tid, s_wt, s_red, s_row); GS();
    conv_stage<false,false>(p0, p1, K1, false, 32, 32, 2048, sm_mask, den0, nullptr, nullptr, nullptr, c, tid, s_wt, s_red, s_row); GS();
    conv_stage<false,true >(p1, p0, K1, true , 32, 32, 2048, sm_mask, 1.f , nullptr, nullptr, nullptr, c, tid, s_wt, s_red, s_row); GS();
    conv_stage<false,false>(p0, p1, K2, false, 32, 32, 2048, sm_mask, den0, nullptr, nullptr, nullptr, c, tid, s_wt, s_red, s_row); GS();
    conv_stage<false,true >(p1, p0, K2, true , 32, 32, 2048, sm_mask, 1.f , nullptr, nullptr, nullptr, c, tid, s_wt, s_red, s_row); GS();
    // K3 down (32->64 @2048) + pool -> p2 (64@1024); p0 preserved as skip0
    conv_stage<false,false>(p0, nullptr, K3, false, 32, 64, 2048, sm_mask, den0, nullptr, p2, sm_M1, c, tid, s_wt, s_red, s_row); GS();
    conv_stage<false,false>(p2, p1, K4, false, 64, 64, 1024, sm_M1, den1, nullptr, nullptr, nullptr, c, tid, s_wt, s_red, s_row); GS();
    conv_stage<false,true >(p1, p2, K4, true , 64, 64, 1024, sm_M1, 1.f , nullptr, nullptr, nullptr, c, tid, s_wt, s_red, s_row); GS();
    conv_stage<false,false>(p2, p1, K5, false, 64, 64, 1024, sm_M1, den1, nullptr, nullptr, nullptr, c, tid, s_wt, s_red, s_row); GS();
    conv_stage<false,true >(p1, p2, K5, true , 64, 64, 1024, sm_M1, 1.f , nullptr, nullptr, nullptr, c, tid, s_wt, s_red, s_row); GS();
    // K6 down (64->128 @1024) + pool -> p3 (128@512); p2 preserved as skip1
    conv_stage<false,false>(p2, nullptr, K6, false, 64, 128, 1024, sm_M1, den1, nullptr, p3, sm_M2, c, tid, s_wt, s_red, s_row); GS();
    // up path
    // K6T: upsample p3 (128@512 -> 1024), convT, IN, relu, +skip p2 -> p1
    conv_stage<true ,false>(p3, p1, K6, true , 128, 64, 1024, sm_M1, den1, p2, nullptr, nullptr, c, tid, s_wt, s_red, s_row); GS();
    conv_stage<false,false>(p1, p2, K5, true , 64, 64, 1024, sm_M1, den1, nullptr, nullptr, nullptr, c, tid, s_wt, s_red, s_row); GS();
    conv_stage<false,true >(p2, p1, K5, false, 64, 64, 1024, sm_M1, 1.f , nullptr, nullptr, nullptr, c, tid, s_wt, s_red, s_row); GS();
    conv_stage<false,false>(p1, p2, K4, true , 64, 64, 1024, sm_M1, den1, nullptr, nullptr, nullptr, c, tid, s_wt, s_red, s_row); GS();
    conv_stage<false,true >(p2, p1, K4, false, 64, 64, 1024, sm_M1, 1.f , nullptr, nullptr, nullptr, c, tid, s_wt, s_red, s_row); GS();
    // K3T: upsample p1 (64@1024 -> 2048), convT, IN, relu, +skip p0 -> p2
    conv_stage<true ,false>(p1, p2, K3, true , 64, 32, 2048, sm_mask, den0, p0, nullptr, nullptr, c, tid, s_wt, s_red, s_row); GS();
    conv_stage<false,false>(p2, p1, K2, true , 32, 32, 2048, sm_mask, den0, nullptr, nullptr, nullptr, c, tid, s_wt, s_red, s_row); GS();
    conv_stage<false,true >(p1, p2, K2, false, 32, 32, 2048, sm_mask, 1.f , nullptr, nullptr, nullptr, c, tid, s_wt, s_red, s_row); GS();
    conv_stage<false,false>(p2, p1, K1, true , 32, 32, 2048, sm_mask, den0, nullptr, nullptr, nullptr, c, tid, s_wt, s_red, s_row); GS();
    conv_stage<false,true >(p1, p2, K1, false, 32, 32, 2048, sm_mask, 1.f , nullptr, nullptr, nullptr, c, tid, s_wt, s_red, s_row); GS();

    // final W conv + coords override + dist_constraint (one block per batch)
    float* xout = out + (size_t)8 * 2048 * 2048 + (size_t)b * 3 * 2048;
    if (c == 0) dc_stage(p2, x, W, xout, b, tid, sm_mask, den0, ubig, smk, sWl);
    GS();

    // ---- tr2dist: each block does 64 i-rows of its batch ----
    {
        float* y = ubig;
        #pragma unroll
        for (int i = 0; i < 3; ++i)
            *(float4*)(y + tid * 4 + i * 2048) = *(const float4*)(xout + tid * 4 + i * 2048);
        __syncthreads();
        const int j0 = tid * 4;
        const float4 w0 = *(const float4*)(y + j0);
        const float4 w1 = *(const float4*)(y + 2048 + j0);
        const float4 w2 = *(const float4*)(y + 4096 + j0);
        for (int r = 0; r < 64; ++r) {
            const int i = c * 64 + r;
            const float a0 = y[i], a1 = y[2048 + i], a2 = y[4096 + i];
            float4 o;
            {
                float d0 = a0 - w0.x, d1 = a1 - w1.x, d2 = a2 - w2.x;
                o.x = sqrtf(fmaf(d0, d0, fmaf(d1, d1, fmaf(d2, d2, 1e-8f))));
            }
            {
                float d0 = a0 - w0.y, d1 = a1 - w1.y, d2 = a2 - w2.y;
                o.y = sqrtf(fmaf(d0, d0, fmaf(d1, d1, fmaf(d2, d2, 1e-8f))));
            }
            {
                float d0 = a0 - w0.z, d1 = a1 - w1.z, d2 = a2 - w2.z;
                o.z = sqrtf(fmaf(d0, d0, fmaf(d1, d1, fmaf(d2, d2, 1e-8f))));
            }
            {
                float d0 = a0 - w0.w, d1 = a1 - w1.w, d2 = a2 - w2.w;
                o.w = sqrtf(fmaf(d0, d0, fmaf(d1, d1, fmaf(d2, d2, 1e-8f))));
            }
            *(float4*)(out + ((size_t)b * 2048 + i) * 2048 + j0) = o;
        }
    }
    #undef GS
}

// ---------------------------------------------------------------------------
// launch
// ---------------------------------------------------------------------------
extern "C" void kernel_launch(void* const* d_in, const int* in_sizes, int n_in,
                              void* d_out, int out_size, void* d_ws, size_t ws_size,
                              hipStream_t stream)
{
    const float* x    = (const float*)d_in[0];
    const float* mask = (const float*)d_in[1];
    const float* K0   = (const float*)d_in[2];
    const float* K1   = (const float*)d_in[3];
    const float* K2   = (const float*)d_in[4];
    const float* K3   = (const float*)d_in[5];
    const float* K4   = (const float*)d_in[6];
    const float* K5   = (const float*)d_in[7];
    const float* K6   = (const float*)d_in[8];
    const float* W    = (const float*)d_in[9];
    float* out = (float*)d_out;
    float* ws  = (float*)d_ws;
    (void)in_sizes; (void)n_in; (void)out_size; (void)ws_size;

    const size_t S = 65536;
    float* B0 = ws;
    float* B1 = ws + 8 * S;
    float* B2 = ws + 16 * S;
    float* B3 = ws + 24 * S;

    void* args[] = {
        (void*)&x, (void*)&mask, (void*)&K0, (void*)&K1, (void*)&K2, (void*)&K3,
        (void*)&K4, (void*)&K5, (void*)&K6, (void*)&W,
        (void*)&out, (void*)&B0, (void*)&B1, (void*)&B2, (void*)&B3
    };
    hipLaunchCooperativeKernel((const void*)vnet_all, dim3(256), dim3(512),
                               args, 0, stream);
}

// Round 4
// 589.290 us; speedup vs baseline: 1.9312x; 1.9312x over previous
//
#include <hip/hip_runtime.h>
#include <math.h>

#define HSTEP 0.1f
#define EPS_IN 1e-5f
#define BIGF 1e10f
#define DCF 3.79f

// ---------------------------------------------------------------------------
// Fused conv stage kernel (standalone; body verified in round 3).
//   CIR  (AXPY=false): y = conv(x)*m -> IN -> relu (+skip) [-> fused avg-pool]
//   AXPY (AXPY=true) : xc -= HSTEP * conv(z) * m
//   UPS: read source at half resolution (fused jnp.repeat upsample * mask).
// Block: 512 threads. NS=2048: 1 co/block (T=512). NS=1024: 2 co/block (T=256).
// ---------------------------------------------------------------------------
template<int CIN, int NS, bool UPS, bool AXPY>
__global__ void __launch_bounds__(512)
conv_k(const float* __restrict__ in, float* __restrict__ out,
       const float* __restrict__ Kw, int Cout, int TR,
       const float* __restrict__ mask, const float* __restrict__ den_g,
       const float* __restrict__ skip, float* __restrict__ pool,
       const float* __restrict__ mhalf)
{
    constexpr int T = (NS == 2048) ? 512 : 256;
    constexpr int P = (NS == 2048) ? 1 : 2;
    __shared__ float swt_s[P * CIN * 3];
    __shared__ float s_red[32];
    __shared__ __align__(16) float s_row[2048];

    const int tid  = threadIdx.x;
    const int grp  = (P == 2) ? (tid >> 8) : 0;
    const int tsub = (P == 2) ? (tid & 255) : tid;
    const int cpb  = Cout / P;                  // co-groups per batch
    const int b    = blockIdx.x / cpb;
    const int co   = (blockIdx.x % cpb) * P + grp;
    float* swt = swt_s + grp * CIN * 3;

    for (int i = tsub; i < CIN * 3; i += T) {
        int ci = i / 3, k = i % 3;
        swt[i] = TR ? Kw[((size_t)ci * Cout + co) * 3 + (2 - k)]
                    : Kw[((size_t)co * CIN + ci) * 3 + k];
    }
    __syncthreads();

    const int srcw = UPS ? (NS >> 1) : NS;
    const float* in_b = in + (size_t)b * CIN * srcw;
    const float* mrow = mask + (size_t)b * NS;

    const int n0 = tsub * 4;
    const float4 mv = *(const float4*)(mrow + n0);
    float a0 = 0.f, a1 = 0.f, a2 = 0.f, a3 = 0.f;
    #pragma unroll 4
    for (int ci = 0; ci < CIN; ++ci) {
        const float* src = in_b + (size_t)ci * srcw;
        float xl, x0, x1, x2, x3, xr;
        if (!UPS) {
            const float4 v = *(const float4*)(src + n0);
            x0 = v.x; x1 = v.y; x2 = v.z; x3 = v.w;
            xl = (n0 > 0)      ? src[n0 - 1] : 0.f;
            xr = (n0 + 4 < NS) ? src[n0 + 4] : 0.f;
        } else {
            const float2 s = *(const float2*)(src + (n0 >> 1));
            x0 = s.x * mv.x; x1 = s.x * mv.y;
            x2 = s.y * mv.z; x3 = s.y * mv.w;
            xl = (n0 > 0)      ? src[(n0 - 1) >> 1] * mrow[n0 - 1] : 0.f;
            xr = (n0 + 4 < NS) ? src[(n0 + 4) >> 1] * mrow[n0 + 4] : 0.f;
        }
        const float w0 = swt[ci * 3], w1 = swt[ci * 3 + 1], w2 = swt[ci * 3 + 2];
        a0 = fmaf(w0, xl, fmaf(w1, x0, fmaf(w2, x1, a0)));
        a1 = fmaf(w0, x0, fmaf(w1, x1, fmaf(w2, x2, a1)));
        a2 = fmaf(w0, x1, fmaf(w1, x2, fmaf(w2, x3, a2)));
        a3 = fmaf(w0, x2, fmaf(w1, x3, fmaf(w2, xr, a3)));
    }
    const float v0 = a0 * mv.x, v1 = a1 * mv.y, v2 = a2 * mv.z, v3 = a3 * mv.w;
    float* orow = out ? out + ((size_t)b * Cout + co) * NS + n0 : nullptr;

    if constexpr (AXPY) {
        float4 cur = *(const float4*)orow;
        float4 rr;
        rr.x = cur.x - HSTEP * v0; rr.y = cur.y - HSTEP * v1;
        rr.z = cur.z - HSTEP * v2; rr.w = cur.w - HSTEP * v3;
        *(float4*)orow = rr;
    } else {
        float ls = v0 + v1 + v2 + v3;
        float lq = v0 * v0 + v1 * v1 + v2 * v2 + v3 * v3;
        #pragma unroll
        for (int off = 32; off > 0; off >>= 1) {
            ls += __shfl_down(ls, off);
            lq += __shfl_down(lq, off);
        }
        const int wig = tsub >> 6;
        const int wpg = T >> 6;
        if ((tsub & 63) == 0) { s_red[grp * 16 + wig * 2] = ls; s_red[grp * 16 + wig * 2 + 1] = lq; }
        __syncthreads();
        float ts = 0.f, tq = 0.f;
        for (int i2 = 0; i2 < wpg; ++i2) { ts += s_red[grp * 16 + i2 * 2]; tq += s_red[grp * 16 + i2 * 2 + 1]; }
        const float den  = den_g[b];
        const float mean = ts / den;
        const float inv  = 1.f / sqrtf(tq / den - mean * mean + EPS_IN);
        float r0 = fmaxf((v0 - mean * mv.x) * inv, 0.f);
        float r1 = fmaxf((v1 - mean * mv.y) * inv, 0.f);
        float r2 = fmaxf((v2 - mean * mv.z) * inv, 0.f);
        float r3 = fmaxf((v3 - mean * mv.w) * inv, 0.f);
        if (skip) {
            const float4 sk = *(const float4*)(skip + ((size_t)b * Cout + co) * NS + n0);
            r0 += sk.x; r1 += sk.y; r2 += sk.z; r3 += sk.w;
        }
        if (orow) {
            float4 rr; rr.x = r0; rr.y = r1; rr.z = r2; rr.w = r3;
            *(float4*)orow = rr;
        }
        if (pool) {
            float* srow = s_row + grp * NS;
            srow[n0] = r0; srow[n0 + 1] = r1; srow[n0 + 2] = r2; srow[n0 + 3] = r3;
            __syncthreads();
            const int Nh = NS >> 1;
            if (tsub < (T >> 1)) {
                const int np0 = tsub * 4;
                const float4 mh = *(const float4*)(mhalf + (size_t)b * Nh + np0);
                float zm1 = (np0 > 0) ? srow[2 * np0 - 1] : 0.f;
                float4 p;
                p.x = (zm1 + srow[2*np0] + srow[2*np0+1]) * (1.f/3.f) * mh.x;
                p.y = (srow[2*np0+1] + srow[2*np0+2] + srow[2*np0+3]) * (1.f/3.f) * mh.y;
                p.z = (srow[2*np0+3] + srow[2*np0+4] + srow[2*np0+5]) * (1.f/3.f) * mh.z;
                p.w = (srow[2*np0+5] + srow[2*np0+6] + srow[2*np0+7]) * (1.f/3.f) * mh.w;
                *(float4*)(pool + ((size_t)b * Cout + co) * Nh + np0) = p;
            }
        }
    }
}

// ---------------------------------------------------------------------------
// fused mask pipeline: DEN0, M1, DEN1, M2 (verified round 2)
// ---------------------------------------------------------------------------
__device__ inline float block_sum1(float v, float* sred) {
    #pragma unroll
    for (int off = 32; off > 0; off >>= 1) v += __shfl_down(v, off);
    int wid = threadIdx.x >> 6;
    int nw  = blockDim.x >> 6;
    if ((threadIdx.x & 63) == 0) sred[wid] = v;
    __syncthreads();
    float total = 0.f;
    for (int i = 0; i < nw; ++i) total += sred[i];
    __syncthreads();
    return total;
}

__global__ void __launch_bounds__(256)
mask_prep_kernel(const float* __restrict__ mask, float* __restrict__ M1,
                 float* __restrict__ M2, float* __restrict__ d0, float* __restrict__ d1)
{
    __shared__ float sm1[1024];
    __shared__ float sredf[4];
    int b = blockIdx.x, tid = threadIdx.x;
    const float* mr = mask + (size_t)b * 2048;

    float s0 = 0.f;
    for (int n = tid; n < 2048; n += 256) s0 += mr[n];
    float t0 = block_sum1(s0, sredf);
    if (tid == 0) d0[b] = t0;

    for (int n = tid; n < 1024; n += 256) {
        float s = mr[2 * n];
        if (2 * n - 1 >= 0)   s += mr[2 * n - 1];
        if (2 * n + 1 < 2048) s += mr[2 * n + 1];
        float v = (s * (1.f / 3.f) >= 0.5f) ? 1.f : 0.f;
        sm1[n] = v;
        M1[(size_t)b * 1024 + n] = v;
    }
    __syncthreads();
    float s1 = 0.f;
    for (int n = tid; n < 1024; n += 256) s1 += sm1[n];
    float t1 = block_sum1(s1, sredf);
    if (tid == 0) d1[b] = t1;

    for (int n = tid; n < 512; n += 256) {
        float s = sm1[2 * n];
        if (2 * n - 1 >= 0)   s += sm1[2 * n - 1];
        if (2 * n + 1 < 1024) s += sm1[2 * n + 1];
        M2[(size_t)b * 512 + n] = (s * (1.f / 3.f) >= 0.5f) ? 1.f : 0.f;
    }
}

// ---------------------------------------------------------------------------
// fused: final W conv + coords override + dist_constraint (verified round 2)
// ---------------------------------------------------------------------------
__global__ void __launch_bounds__(1024)
dc_all_kernel(const float* __restrict__ xc32, const float* __restrict__ x,
              const float* __restrict__ W, const float* __restrict__ mask,
              const float* __restrict__ den, float* __restrict__ xout, int N)
{
    __shared__ float sX[3][2048];
    __shared__ float sD[3][2048];
    __shared__ float sM[2048];
    __shared__ unsigned long long smk[32];
    __shared__ float sW[96];

    const int b = blockIdx.x, tid = threadIdx.x;
    if (tid < 96) sW[tid] = W[tid];
    __syncthreads();

    const float* xb      = xc32 + (size_t)b * 32 * N;
    const float* flagrow = x + ((size_t)b * 24 + 23) * N;

    #pragma unroll
    for (int r = 0; r < 2; ++r) {
        int n = tid + r * 1024;
        float mk = mask[(size_t)b * N + n];
        float fl = flagrow[n];
        float v0 = 0.f, v1 = 0.f, v2 = 0.f;
        #pragma unroll 8
        for (int ci = 0; ci < 32; ++ci) {
            float xv = xb[(size_t)ci * N + n];
            v0 = fmaf(sW[0 * 32 + ci], xv, v0);
            v1 = fmaf(sW[1 * 32 + ci], xv, v1);
            v2 = fmaf(sW[2 * 32 + ci], xv, v2);
        }
        v0 *= mk; v1 *= mk; v2 *= mk;
        bool fixed = (fl == 1.f);
        if (fixed) {
            v0 = x[((size_t)b * 24 + 20) * N + n];
            v1 = x[((size_t)b * 24 + 21) * N + n];
            v2 = x[((size_t)b * 24 + 22) * N + n];
        }
        sX[0][n] = v0; sX[1][n] = v1; sX[2][n] = v2; sM[n] = mk;
        unsigned long long bm = __ballot(fixed);
        if ((tid & 63) == 0) smk[n >> 6] = bm;
    }
    __syncthreads();

    #pragma unroll
    for (int r = 0; r < 2; ++r) {
        int n = tid + r * 1024;
        if (n < N - 1) {
            float d0 = sX[0][n + 1] - sX[0][n];
            float d1 = sX[1][n + 1] - sX[1][n];
            float d2 = sX[2][n + 1] - sX[2][n];
            float d  = d0 * d0 + d1 * d1 + d2 * d2;
            bool avM = floorf((sM[n] + sM[n + 1]) * 0.5f) < 0.5f;
            if (avM) {
                sD[0][n] = 0.f; sD[1][n] = 0.f; sD[2][n] = 0.f;
            } else {
                float sq = sqrtf(d);
                sD[0][n] = (d0 / sq) * DCF;
                sD[1][n] = (d1 / sq) * DCF;
                sD[2][n] = (d2 / sq) * DCF;
            }
        }
    }
    __syncthreads();

    int len = (int)den[b];

    #pragma unroll
    for (int r = 0; r < 2; ++r) {
        int j  = tid + r * 1024;
        int cc = j >> 6, jl = j & 63;

        unsigned long long below = smk[cc] & (~0ull >> (63 - jl));
        int p = -1;
        if (below) p = (cc << 6) + 63 - __clzll(below);
        else {
            for (int c2 = cc - 1; c2 >= 0; --c2) {
                unsigned long long m = smk[c2];
                if (m) { p = (c2 << 6) + 63 - __clzll(m); break; }
            }
        }
        float l0, l1, l2, wl;
        if (p >= 0) {
            wl = (float)(j - p);
            l0 = sX[0][p]; l1 = sX[1][p]; l2 = sX[2][p];
            int kend = min(j, len - 1);
            for (int k = p; k < kend; ++k) {
                l0 += sD[0][k]; l1 += sD[1][k]; l2 += sD[2][k];
            }
        } else { wl = BIGF; l0 = sX[0][j]; l1 = sX[1][j]; l2 = sX[2][j]; }

        unsigned long long above = smk[cc] & (~0ull << jl);
        int q = -1;
        if (above) q = (cc << 6) + __ffsll(above) - 1;
        else {
            for (int c2 = cc + 1; c2 < 32; ++c2) {
                unsigned long long m = smk[c2];
                if (m) { q = (c2 << 6) + __ffsll(m) - 1; break; }
            }
        }
        float r0, r1, r2, wr;
        if (q >= 0) {
            wr = (float)(q - j);
            r0 = sX[0][q]; r1 = sX[1][q]; r2 = sX[2][q];
            for (int k = q - 1; k >= j; --k) {
                r0 -= sD[0][k]; r1 -= sD[1][k]; r2 -= sD[2][k];
            }
        } else { wr = BIGF; r0 = sX[0][j]; r1 = sX[1][j]; r2 = sX[2][j]; }

        float ws_ = wl + wr, cl, cr;
        if (ws_ == 0.f) { cl = 0.5f; cr = 0.5f; }
        else            { cl = wr / ws_; cr = wl / ws_; }
        float mk = sM[j];
        xout[((size_t)b * 3 + 0) * N + j] = (l0 * cl + r0 * cr) * mk;
        xout[((size_t)b * 3 + 1) * N + j] = (l1 * cl + r1 * cr) * mk;
        xout[((size_t)b * 3 + 2) * N + j] = (l2 * cl + r2 * cr) * mk;
    }
}

// ---------------------------------------------------------------------------
// pairwise distances: 32-row tiles, y staged in LDS, float4 stores
// ---------------------------------------------------------------------------
__global__ void __launch_bounds__(256)
tr2dist_kernel(const float* __restrict__ Y, float* __restrict__ out, int N)
{
    __shared__ __align__(16) float y[6144];
    const int b    = blockIdx.x >> 6;
    const int tile = blockIdx.x & 63;
    const int tid  = threadIdx.x;
    const float* yb = Y + (size_t)b * 3 * 2048;
    #pragma unroll
    for (int k = 0; k < 6; ++k)
        *(float4*)(y + (tid + k * 256) * 4) = *(const float4*)(yb + (tid + k * 256) * 4);
    __syncthreads();

    const int j0 = tid * 8;
    float w0[8], w1[8], w2[8];
    #pragma unroll
    for (int k = 0; k < 8; ++k) {
        w0[k] = y[j0 + k]; w1[k] = y[2048 + j0 + k]; w2[k] = y[4096 + j0 + k];
    }
    for (int r = 0; r < 32; ++r) {
        const int i = tile * 32 + r;
        const float a0 = y[i], a1 = y[2048 + i], a2 = y[4096 + i];
        float o[8];
        #pragma unroll
        for (int k = 0; k < 8; ++k) {
            float d0 = a0 - w0[k], d1 = a1 - w1[k], d2 = a2 - w2[k];
            o[k] = sqrtf(fmaf(d0, d0, fmaf(d1, d1, fmaf(d2, d2, 1e-8f))));
        }
        float* orow = out + ((size_t)b * 2048 + i) * 2048 + j0;
        float4 q0; q0.x = o[0]; q0.y = o[1]; q0.z = o[2]; q0.w = o[3];
        float4 q1; q1.x = o[4]; q1.y = o[5]; q1.z = o[6]; q1.w = o[7];
        *(float4*)orow = q0;
        *(float4*)(orow + 4) = q1;
    }
}

// ---------------------------------------------------------------------------
// launch
// ---------------------------------------------------------------------------
extern "C" void kernel_launch(void* const* d_in, const int* in_sizes, int n_in,
                              void* d_out, int out_size, void* d_ws, size_t ws_size,
                              hipStream_t stream)
{
    const float* x    = (const float*)d_in[0];
    const float* mask = (const float*)d_in[1];
    const float* K0   = (const float*)d_in[2];
    const float* K1   = (const float*)d_in[3];
    const float* K2   = (const float*)d_in[4];
    const float* K3   = (const float*)d_in[5];
    const float* K4   = (const float*)d_in[6];
    const float* K5   = (const float*)d_in[7];
    const float* K6   = (const float*)d_in[8];
    const float* W    = (const float*)d_in[9];
    float* out = (float*)d_out;
    float* ws  = (float*)d_ws;
    (void)in_sizes; (void)n_in; (void)out_size; (void)ws_size;

    const int B = 8, N = 2048;
    const size_t S = 65536;
    float* B0 = ws;
    float* B1 = ws + 8 * S;
    float* B2 = ws + 16 * S;
    float* B3 = ws + 24 * S;
    float* M1   = ws + 32 * S;
    float* M2   = M1 + 8 * 1024;
    float* DEN0 = M2 + 8 * 512;
    float* DEN1 = DEN0 + 8;
    float* XOUT = out + (size_t)B * N * N;
    const float* NUL = nullptr;

    mask_prep_kernel<<<8, 256, 0, stream>>>(mask, M1, M2, DEN0, DEN1);

    // ---- down path @2048 ----
    conv_k<24,2048,false,false><<<256, 512, 0, stream>>>(x,  B0, K0, 32, 0, mask, DEN0, NUL, nullptr, NUL);
    conv_k<32,2048,false,false><<<256, 512, 0, stream>>>(B0, B1, K1, 32, 0, mask, DEN0, NUL, nullptr, NUL);
    conv_k<32,2048,false,true ><<<256, 512, 0, stream>>>(B1, B0, K1, 32, 1, mask, DEN0, NUL, nullptr, NUL);
    conv_k<32,2048,false,false><<<256, 512, 0, stream>>>(B0, B1, K2, 32, 0, mask, DEN0, NUL, nullptr, NUL);
    conv_k<32,2048,false,true ><<<256, 512, 0, stream>>>(B1, B0, K2, 32, 1, mask, DEN0, NUL, nullptr, NUL);
    // K3 (32->64) + fused pool -> B2 (64@1024); B0 preserved as skip0
    conv_k<32,2048,false,false><<<512, 512, 0, stream>>>(B0, nullptr, K3, 64, 0, mask, DEN0, NUL, B2, M1);

    // ---- down path @1024 ----
    conv_k<64,1024,false,false><<<256, 512, 0, stream>>>(B2, B1, K4, 64, 0, M1, DEN1, NUL, nullptr, NUL);
    conv_k<64,1024,false,true ><<<256, 512, 0, stream>>>(B1, B2, K4, 64, 1, M1, DEN1, NUL, nullptr, NUL);
    conv_k<64,1024,false,false><<<256, 512, 0, stream>>>(B2, B1, K5, 64, 0, M1, DEN1, NUL, nullptr, NUL);
    conv_k<64,1024,false,true ><<<256, 512, 0, stream>>>(B1, B2, K5, 64, 1, M1, DEN1, NUL, nullptr, NUL);
    // K6 (64->128) + fused pool -> B3 (128@512); B2 preserved as skip1
    conv_k<64,1024,false,false><<<512, 512, 0, stream>>>(B2, nullptr, K6, 128, 0, M1, DEN1, NUL, B3, M2);

    // ---- up path @1024 ----
    // K6T: fused upsample (B3 128@512 -> @1024) + convT + IN + relu + skip B2
    conv_k<128,1024,true ,false><<<256, 512, 0, stream>>>(B3, B1, K6, 64, 1, M1, DEN1, B2, nullptr, NUL);
    conv_k<64,1024,false,false><<<256, 512, 0, stream>>>(B1, B2, K5, 64, 1, M1, DEN1, NUL, nullptr, NUL);
    conv_k<64,1024,false,true ><<<256, 512, 0, stream>>>(B2, B1, K5, 64, 0, M1, DEN1, NUL, nullptr, NUL);
    conv_k<64,1024,false,false><<<256, 512, 0, stream>>>(B1, B2, K4, 64, 1, M1, DEN1, NUL, nullptr, NUL);
    conv_k<64,1024,false,true ><<<256, 512, 0, stream>>>(B2, B1, K4, 64, 0, M1, DEN1, NUL, nullptr, NUL);

    // ---- up path @2048 ----
    // K3T: fused upsample (B1 64@1024 -> @2048) + convT + IN + relu + skip B0
    conv_k<64,2048,true ,false><<<256, 512, 0, stream>>>(B1, B2, K3, 32, 1, mask, DEN0, B0, nullptr, NUL);
    conv_k<32,2048,false,false><<<256, 512, 0, stream>>>(B2, B1, K2, 32, 1, mask, DEN0, NUL, nullptr, NUL);
    conv_k<32,2048,false,true ><<<256, 512, 0, stream>>>(B1, B2, K2, 32, 0, mask, DEN0, NUL, nullptr, NUL);
    conv_k<32,2048,false,false><<<256, 512, 0, stream>>>(B2, B1, K1, 32, 1, mask, DEN0, NUL, nullptr, NUL);
    conv_k<32,2048,false,true ><<<256, 512, 0, stream>>>(B1, B2, K1, 32, 0, mask, DEN0, NUL, nullptr, NUL);

    // final W conv + coords override + dist_constraint
    dc_all_kernel<<<8, 1024, 0, stream>>>(B2, x, W, mask, DEN0, XOUT, N);

    // pairwise distance matrix
    tr2dist_kernel<<<8 * 64, 256, 0, stream>>>(XOUT, out, N);
}

// Round 5
// 542.773 us; speedup vs baseline: 2.0967x; 1.0857x over previous
//
#include <hip/hip_runtime.h>
#include <math.h>

#define HSTEP 0.1f
#define EPS_IN 1e-5f
#define BIGF 1e10f
#define DCF 3.79f

typedef float v4f __attribute__((ext_vector_type(4)));

// ---------------------------------------------------------------------------
// Fused conv stage kernel (standalone; body verified in rounds 3/4).
//   CIR  (AXPY=false): y = conv(x)*m -> IN -> relu (+skip) [-> fused avg-pool]
//   AXPY (AXPY=true) : xc -= HSTEP * conv(z) * m
//   UPS: read source at half resolution (fused jnp.repeat upsample * mask).
// Block: 512 threads. NS=2048: 1 co/block (T=512). NS=1024: 2 co/block (T=256).
// ---------------------------------------------------------------------------
template<int CIN, int NS, bool UPS, bool AXPY>
__global__ void __launch_bounds__(512)
conv_k(const float* __restrict__ in, float* __restrict__ out,
       const float* __restrict__ Kw, int Cout, int TR,
       const float* __restrict__ mask, const float* __restrict__ den_g,
       const float* __restrict__ skip, float* __restrict__ pool,
       const float* __restrict__ mhalf)
{
    constexpr int T = (NS == 2048) ? 512 : 256;
    constexpr int P = (NS == 2048) ? 1 : 2;
    __shared__ float swt_s[P * CIN * 3];
    __shared__ float s_red[32];
    __shared__ __align__(16) float s_row[2048];

    const int tid  = threadIdx.x;
    const int grp  = (P == 2) ? (tid >> 8) : 0;
    const int tsub = (P == 2) ? (tid & 255) : tid;
    const int cpb  = Cout / P;                  // co-groups per batch
    const int b    = blockIdx.x / cpb;
    const int co   = (blockIdx.x % cpb) * P + grp;
    float* swt = swt_s + grp * CIN * 3;

    for (int i = tsub; i < CIN * 3; i += T) {
        int ci = i / 3, k = i % 3;
        swt[i] = TR ? Kw[((size_t)ci * Cout + co) * 3 + (2 - k)]
                    : Kw[((size_t)co * CIN + ci) * 3 + k];
    }
    __syncthreads();

    const int srcw = UPS ? (NS >> 1) : NS;
    const float* in_b = in + (size_t)b * CIN * srcw;
    const float* mrow = mask + (size_t)b * NS;

    const int n0 = tsub * 4;
    const float4 mv = *(const float4*)(mrow + n0);
    float a0 = 0.f, a1 = 0.f, a2 = 0.f, a3 = 0.f;
    #pragma unroll 4
    for (int ci = 0; ci < CIN; ++ci) {
        const float* src = in_b + (size_t)ci * srcw;
        float xl, x0, x1, x2, x3, xr;
        if (!UPS) {
            const float4 v = *(const float4*)(src + n0);
            x0 = v.x; x1 = v.y; x2 = v.z; x3 = v.w;
            xl = (n0 > 0)      ? src[n0 - 1] : 0.f;
            xr = (n0 + 4 < NS) ? src[n0 + 4] : 0.f;
        } else {
            const float2 s = *(const float2*)(src + (n0 >> 1));
            x0 = s.x * mv.x; x1 = s.x * mv.y;
            x2 = s.y * mv.z; x3 = s.y * mv.w;
            xl = (n0 > 0)      ? src[(n0 - 1) >> 1] * mrow[n0 - 1] : 0.f;
            xr = (n0 + 4 < NS) ? src[(n0 + 4) >> 1] * mrow[n0 + 4] : 0.f;
        }
        const float w0 = swt[ci * 3], w1 = swt[ci * 3 + 1], w2 = swt[ci * 3 + 2];
        a0 = fmaf(w0, xl, fmaf(w1, x0, fmaf(w2, x1, a0)));
        a1 = fmaf(w0, x0, fmaf(w1, x1, fmaf(w2, x2, a1)));
        a2 = fmaf(w0, x1, fmaf(w1, x2, fmaf(w2, x3, a2)));
        a3 = fmaf(w0, x2, fmaf(w1, x3, fmaf(w2, xr, a3)));
    }
    const float v0 = a0 * mv.x, v1 = a1 * mv.y, v2 = a2 * mv.z, v3 = a3 * mv.w;
    float* orow = out ? out + ((size_t)b * Cout + co) * NS + n0 : nullptr;

    if constexpr (AXPY) {
        float4 cur = *(const float4*)orow;
        float4 rr;
        rr.x = cur.x - HSTEP * v0; rr.y = cur.y - HSTEP * v1;
        rr.z = cur.z - HSTEP * v2; rr.w = cur.w - HSTEP * v3;
        *(float4*)orow = rr;
    } else {
        float ls = v0 + v1 + v2 + v3;
        float lq = v0 * v0 + v1 * v1 + v2 * v2 + v3 * v3;
        #pragma unroll
        for (int off = 32; off > 0; off >>= 1) {
            ls += __shfl_down(ls, off);
            lq += __shfl_down(lq, off);
        }
        const int wig = tsub >> 6;
        const int wpg = T >> 6;
        if ((tsub & 63) == 0) { s_red[grp * 16 + wig * 2] = ls; s_red[grp * 16 + wig * 2 + 1] = lq; }
        __syncthreads();
        float ts = 0.f, tq = 0.f;
        for (int i2 = 0; i2 < wpg; ++i2) { ts += s_red[grp * 16 + i2 * 2]; tq += s_red[grp * 16 + i2 * 2 + 1]; }
        const float den  = den_g[b];
        const float mean = ts / den;
        const float inv  = 1.f / sqrtf(tq / den - mean * mean + EPS_IN);
        float r0 = fmaxf((v0 - mean * mv.x) * inv, 0.f);
        float r1 = fmaxf((v1 - mean * mv.y) * inv, 0.f);
        float r2 = fmaxf((v2 - mean * mv.z) * inv, 0.f);
        float r3 = fmaxf((v3 - mean * mv.w) * inv, 0.f);
        if (skip) {
            const float4 sk = *(const float4*)(skip + ((size_t)b * Cout + co) * NS + n0);
            r0 += sk.x; r1 += sk.y; r2 += sk.z; r3 += sk.w;
        }
        if (orow) {
            float4 rr; rr.x = r0; rr.y = r1; rr.z = r2; rr.w = r3;
            *(float4*)orow = rr;
        }
        if (pool) {
            float* srow = s_row + grp * NS;
            srow[n0] = r0; srow[n0 + 1] = r1; srow[n0 + 2] = r2; srow[n0 + 3] = r3;
            __syncthreads();
            const int Nh = NS >> 1;
            if (tsub < (T >> 1)) {
                const int np0 = tsub * 4;
                const float4 mh = *(const float4*)(mhalf + (size_t)b * Nh + np0);
                float zm1 = (np0 > 0) ? srow[2 * np0 - 1] : 0.f;
                float4 p;
                p.x = (zm1 + srow[2*np0] + srow[2*np0+1]) * (1.f/3.f) * mh.x;
                p.y = (srow[2*np0+1] + srow[2*np0+2] + srow[2*np0+3]) * (1.f/3.f) * mh.y;
                p.z = (srow[2*np0+3] + srow[2*np0+4] + srow[2*np0+5]) * (1.f/3.f) * mh.z;
                p.w = (srow[2*np0+5] + srow[2*np0+6] + srow[2*np0+7]) * (1.f/3.f) * mh.w;
                *(float4*)(pool + ((size_t)b * Cout + co) * Nh + np0) = p;
            }
        }
    }
}

// ---------------------------------------------------------------------------
// fused mask pipeline: DEN0, M1, DEN1, M2 (verified round 2)
// ---------------------------------------------------------------------------
__device__ inline float block_sum1(float v, float* sred) {
    #pragma unroll
    for (int off = 32; off > 0; off >>= 1) v += __shfl_down(v, off);
    int wid = threadIdx.x >> 6;
    int nw  = blockDim.x >> 6;
    if ((threadIdx.x & 63) == 0) sred[wid] = v;
    __syncthreads();
    float total = 0.f;
    for (int i = 0; i < nw; ++i) total += sred[i];
    __syncthreads();
    return total;
}

__global__ void __launch_bounds__(256)
mask_prep_kernel(const float* __restrict__ mask, float* __restrict__ M1,
                 float* __restrict__ M2, float* __restrict__ d0, float* __restrict__ d1)
{
    __shared__ float sm1[1024];
    __shared__ float sredf[4];
    int b = blockIdx.x, tid = threadIdx.x;
    const float* mr = mask + (size_t)b * 2048;

    float s0 = 0.f;
    for (int n = tid; n < 2048; n += 256) s0 += mr[n];
    float t0 = block_sum1(s0, sredf);
    if (tid == 0) d0[b] = t0;

    for (int n = tid; n < 1024; n += 256) {
        float s = mr[2 * n];
        if (2 * n - 1 >= 0)   s += mr[2 * n - 1];
        if (2 * n + 1 < 2048) s += mr[2 * n + 1];
        float v = (s * (1.f / 3.f) >= 0.5f) ? 1.f : 0.f;
        sm1[n] = v;
        M1[(size_t)b * 1024 + n] = v;
    }
    __syncthreads();
    float s1 = 0.f;
    for (int n = tid; n < 1024; n += 256) s1 += sm1[n];
    float t1 = block_sum1(s1, sredf);
    if (tid == 0) d1[b] = t1;

    for (int n = tid; n < 512; n += 256) {
        float s = sm1[2 * n];
        if (2 * n - 1 >= 0)   s += sm1[2 * n - 1];
        if (2 * n + 1 < 1024) s += sm1[2 * n + 1];
        M2[(size_t)b * 512 + n] = (s * (1.f / 3.f) >= 0.5f) ? 1.f : 0.f;
    }
}

// ---------------------------------------------------------------------------
// fused: final W conv + coords override + dist_constraint (verified round 2)
// ---------------------------------------------------------------------------
__global__ void __launch_bounds__(1024)
dc_all_kernel(const float* __restrict__ xc32, const float* __restrict__ x,
              const float* __restrict__ W, const float* __restrict__ mask,
              const float* __restrict__ den, float* __restrict__ xout, int N)
{
    __shared__ float sX[3][2048];
    __shared__ float sD[3][2048];
    __shared__ float sM[2048];
    __shared__ unsigned long long smk[32];
    __shared__ float sW[96];

    const int b = blockIdx.x, tid = threadIdx.x;
    if (tid < 96) sW[tid] = W[tid];
    __syncthreads();

    const float* xb      = xc32 + (size_t)b * 32 * N;
    const float* flagrow = x + ((size_t)b * 24 + 23) * N;

    #pragma unroll
    for (int r = 0; r < 2; ++r) {
        int n = tid + r * 1024;
        float mk = mask[(size_t)b * N + n];
        float fl = flagrow[n];
        float v0 = 0.f, v1 = 0.f, v2 = 0.f;
        #pragma unroll 8
        for (int ci = 0; ci < 32; ++ci) {
            float xv = xb[(size_t)ci * N + n];
            v0 = fmaf(sW[0 * 32 + ci], xv, v0);
            v1 = fmaf(sW[1 * 32 + ci], xv, v1);
            v2 = fmaf(sW[2 * 32 + ci], xv, v2);
        }
        v0 *= mk; v1 *= mk; v2 *= mk;
        bool fixed = (fl == 1.f);
        if (fixed) {
            v0 = x[((size_t)b * 24 + 20) * N + n];
            v1 = x[((size_t)b * 24 + 21) * N + n];
            v2 = x[((size_t)b * 24 + 22) * N + n];
        }
        sX[0][n] = v0; sX[1][n] = v1; sX[2][n] = v2; sM[n] = mk;
        unsigned long long bm = __ballot(fixed);
        if ((tid & 63) == 0) smk[n >> 6] = bm;
    }
    __syncthreads();

    #pragma unroll
    for (int r = 0; r < 2; ++r) {
        int n = tid + r * 1024;
        if (n < N - 1) {
            float d0 = sX[0][n + 1] - sX[0][n];
            float d1 = sX[1][n + 1] - sX[1][n];
            float d2 = sX[2][n + 1] - sX[2][n];
            float d  = d0 * d0 + d1 * d1 + d2 * d2;
            bool avM = floorf((sM[n] + sM[n + 1]) * 0.5f) < 0.5f;
            if (avM) {
                sD[0][n] = 0.f; sD[1][n] = 0.f; sD[2][n] = 0.f;
            } else {
                float sq = sqrtf(d);
                sD[0][n] = (d0 / sq) * DCF;
                sD[1][n] = (d1 / sq) * DCF;
                sD[2][n] = (d2 / sq) * DCF;
            }
        }
    }
    __syncthreads();

    int len = (int)den[b];

    #pragma unroll
    for (int r = 0; r < 2; ++r) {
        int j  = tid + r * 1024;
        int cc = j >> 6, jl = j & 63;

        unsigned long long below = smk[cc] & (~0ull >> (63 - jl));
        int p = -1;
        if (below) p = (cc << 6) + 63 - __clzll(below);
        else {
            for (int c2 = cc - 1; c2 >= 0; --c2) {
                unsigned long long m = smk[c2];
                if (m) { p = (c2 << 6) + 63 - __clzll(m); break; }
            }
        }
        float l0, l1, l2, wl;
        if (p >= 0) {
            wl = (float)(j - p);
            l0 = sX[0][p]; l1 = sX[1][p]; l2 = sX[2][p];
            int kend = min(j, len - 1);
            for (int k = p; k < kend; ++k) {
                l0 += sD[0][k]; l1 += sD[1][k]; l2 += sD[2][k];
            }
        } else { wl = BIGF; l0 = sX[0][j]; l1 = sX[1][j]; l2 = sX[2][j]; }

        unsigned long long above = smk[cc] & (~0ull << jl);
        int q = -1;
        if (above) q = (cc << 6) + __ffsll(above) - 1;
        else {
            for (int c2 = cc + 1; c2 < 32; ++c2) {
                unsigned long long m = smk[c2];
                if (m) { q = (c2 << 6) + __ffsll(m) - 1; break; }
            }
        }
        float r0, r1, r2, wr;
        if (q >= 0) {
            wr = (float)(q - j);
            r0 = sX[0][q]; r1 = sX[1][q]; r2 = sX[2][q];
            for (int k = q - 1; k >= j; --k) {
                r0 -= sD[0][k]; r1 -= sD[1][k]; r2 -= sD[2][k];
            }
        } else { wr = BIGF; r0 = sX[0][j]; r1 = sX[1][j]; r2 = sX[2][j]; }

        float ws_ = wl + wr, cl, cr;
        if (ws_ == 0.f) { cl = 0.5f; cr = 0.5f; }
        else            { cl = wr / ws_; cr = wl / ws_; }
        float mk = sM[j];
        xout[((size_t)b * 3 + 0) * N + j] = (l0 * cl + r0 * cr) * mk;
        xout[((size_t)b * 3 + 1) * N + j] = (l1 * cl + r1 * cr) * mk;
        xout[((size_t)b * 3 + 2) * N + j] = (l2 * cl + r2 * cr) * mk;
    }
}

// ---------------------------------------------------------------------------
// pairwise distances v2: 2048 blocks (8 rows each), no LDS, fully-coalesced
// nontemporal float4 stores; Y reads are L2-resident broadcasts.
// ---------------------------------------------------------------------------
__global__ void __launch_bounds__(256)
tr2dist_kernel(const float* __restrict__ Y, float* __restrict__ out)
{
    const int b    = blockIdx.x >> 8;     // 8 batches
    const int tile = blockIdx.x & 255;    // 256 tiles of 8 rows
    const int tid  = threadIdx.x;
    const float* yb = Y + (size_t)b * 6144;

    const int jA = tid * 4;               // cols 0..1023 (wave-contiguous)
    const int jB = 1024 + tid * 4;        // cols 1024..2047
    const float4 cA0 = *(const float4*)(yb + jA);
    const float4 cA1 = *(const float4*)(yb + 2048 + jA);
    const float4 cA2 = *(const float4*)(yb + 4096 + jA);
    const float4 cB0 = *(const float4*)(yb + jB);
    const float4 cB1 = *(const float4*)(yb + 2048 + jB);
    const float4 cB2 = *(const float4*)(yb + 4096 + jB);

    #pragma unroll
    for (int r = 0; r < 8; ++r) {
        const int i = tile * 8 + r;
        const float y0 = yb[i], y1 = yb[2048 + i], y2 = yb[4096 + i];
        v4f oA, oB;
        {
            float d0 = y0 - cA0.x, d1 = y1 - cA1.x, d2 = y2 - cA2.x;
            oA.x = sqrtf(fmaf(d0, d0, fmaf(d1, d1, fmaf(d2, d2, 1e-8f))));
            d0 = y0 - cA0.y; d1 = y1 - cA1.y; d2 = y2 - cA2.y;
            oA.y = sqrtf(fmaf(d0, d0, fmaf(d1, d1, fmaf(d2, d2, 1e-8f))));
            d0 = y0 - cA0.z; d1 = y1 - cA1.z; d2 = y2 - cA2.z;
            oA.z = sqrtf(fmaf(d0, d0, fmaf(d1, d1, fmaf(d2, d2, 1e-8f))));
            d0 = y0 - cA0.w; d1 = y1 - cA1.w; d2 = y2 - cA2.w;
            oA.w = sqrtf(fmaf(d0, d0, fmaf(d1, d1, fmaf(d2, d2, 1e-8f))));
        }
        {
            float d0 = y0 - cB0.x, d1 = y1 - cB1.x, d2 = y2 - cB2.x;
            oB.x = sqrtf(fmaf(d0, d0, fmaf(d1, d1, fmaf(d2, d2, 1e-8f))));
            d0 = y0 - cB0.y; d1 = y1 - cB1.y; d2 = y2 - cB2.y;
            oB.y = sqrtf(fmaf(d0, d0, fmaf(d1, d1, fmaf(d2, d2, 1e-8f))));
            d0 = y0 - cB0.z; d1 = y1 - cB1.z; d2 = y2 - cB2.z;
            oB.z = sqrtf(fmaf(d0, d0, fmaf(d1, d1, fmaf(d2, d2, 1e-8f))));
            d0 = y0 - cB0.w; d1 = y1 - cB1.w; d2 = y2 - cB2.w;
            oB.w = sqrtf(fmaf(d0, d0, fmaf(d1, d1, fmaf(d2, d2, 1e-8f))));
        }
        float* orow = out + ((size_t)b * 2048 + i) * 2048;
        __builtin_nontemporal_store(oA, (v4f*)(orow + jA));
        __builtin_nontemporal_store(oB, (v4f*)(orow + jB));
    }
}

// ---------------------------------------------------------------------------
// launch
// ---------------------------------------------------------------------------
extern "C" void kernel_launch(void* const* d_in, const int* in_sizes, int n_in,
                              void* d_out, int out_size, void* d_ws, size_t ws_size,
                              hipStream_t stream)
{
    const float* x    = (const float*)d_in[0];
    const float* mask = (const float*)d_in[1];
    const float* K0   = (const float*)d_in[2];
    const float* K1   = (const float*)d_in[3];
    const float* K2   = (const float*)d_in[4];
    const float* K3   = (const float*)d_in[5];
    const float* K4   = (const float*)d_in[6];
    const float* K5   = (const float*)d_in[7];
    const float* K6   = (const float*)d_in[8];
    const float* W    = (const float*)d_in[9];
    float* out = (float*)d_out;
    float* ws  = (float*)d_ws;
    (void)in_sizes; (void)n_in; (void)out_size; (void)ws_size;

    const int B = 8, N = 2048;
    const size_t S = 65536;
    float* B0 = ws;
    float* B1 = ws + 8 * S;
    float* B2 = ws + 16 * S;
    float* B3 = ws + 24 * S;
    float* M1   = ws + 32 * S;
    float* M2   = M1 + 8 * 1024;
    float* DEN0 = M2 + 8 * 512;
    float* DEN1 = DEN0 + 8;
    float* XOUT = out + (size_t)B * N * N;
    const float* NUL = nullptr;

    mask_prep_kernel<<<8, 256, 0, stream>>>(mask, M1, M2, DEN0, DEN1);

    // ---- down path @2048 ----
    conv_k<24,2048,false,false><<<256, 512, 0, stream>>>(x,  B0, K0, 32, 0, mask, DEN0, NUL, nullptr, NUL);
    conv_k<32,2048,false,false><<<256, 512, 0, stream>>>(B0, B1, K1, 32, 0, mask, DEN0, NUL, nullptr, NUL);
    conv_k<32,2048,false,true ><<<256, 512, 0, stream>>>(B1, B0, K1, 32, 1, mask, DEN0, NUL, nullptr, NUL);
    conv_k<32,2048,false,false><<<256, 512, 0, stream>>>(B0, B1, K2, 32, 0, mask, DEN0, NUL, nullptr, NUL);
    conv_k<32,2048,false,true ><<<256, 512, 0, stream>>>(B1, B0, K2, 32, 1, mask, DEN0, NUL, nullptr, NUL);
    // K3 (32->64) + fused pool -> B2 (64@1024); B0 preserved as skip0
    conv_k<32,2048,false,false><<<512, 512, 0, stream>>>(B0, nullptr, K3, 64, 0, mask, DEN0, NUL, B2, M1);

    // ---- down path @1024 ----
    conv_k<64,1024,false,false><<<256, 512, 0, stream>>>(B2, B1, K4, 64, 0, M1, DEN1, NUL, nullptr, NUL);
    conv_k<64,1024,false,true ><<<256, 512, 0, stream>>>(B1, B2, K4, 64, 1, M1, DEN1, NUL, nullptr, NUL);
    conv_k<64,1024,false,false><<<256, 512, 0, stream>>>(B2, B1, K5, 64, 0, M1, DEN1, NUL, nullptr, NUL);
    conv_k<64,1024,false,true ><<<256, 512, 0, stream>>>(B1, B2, K5, 64, 1, M1, DEN1, NUL, nullptr, NUL);
    // K6 (64->128) + fused pool -> B3 (128@512); B2 preserved as skip1
    conv_k<64,1024,false,false><<<512, 512, 0, stream>>>(B2, nullptr, K6, 128, 0, M1, DEN1, NUL, B3, M2);

    // ---- up path @1024 ----
    // K6T: fused upsample (B3 128@512 -> @1024) + convT + IN + relu + skip B2
    conv_k<128,1024,true ,false><<<256, 512, 0, stream>>>(B3, B1, K6, 64, 1, M1, DEN1, B2, nullptr, NUL);
    conv_k<64,1024,false,false><<<256, 512, 0, stream>>>(B1, B2, K5, 64, 1, M1, DEN1, NUL, nullptr, NUL);
    conv_k<64,1024,false,true ><<<256, 512, 0, stream>>>(B2, B1, K5, 64, 0, M1, DEN1, NUL, nullptr, NUL);
    conv_k<64,1024,false,false><<<256, 512, 0, stream>>>(B1, B2, K4, 64, 1, M1, DEN1, NUL, nullptr, NUL);
    conv_k<64,1024,false,true ><<<256, 512, 0, stream>>>(B2, B1, K4, 64, 0, M1, DEN1, NUL, nullptr, NUL);

    // ---- up path @2048 ----
    // K3T: fused upsample (B1 64@1024 -> @2048) + convT + IN + relu + skip B0
    conv_k<64,2048,true ,false><<<256, 512, 0, stream>>>(B1, B2, K3, 32, 1, mask, DEN0, B0, nullptr, NUL);
    conv_k<32,2048,false,false><<<256, 512, 0, stream>>>(B2, B1, K2, 32, 1, mask, DEN0, NUL, nullptr, NUL);
    conv_k<32,2048,false,true ><<<256, 512, 0, stream>>>(B1, B2, K2, 32, 0, mask, DEN0, NUL, nullptr, NUL);
    conv_k<32,2048,false,false><<<256, 512, 0, stream>>>(B2, B1, K1, 32, 1, mask, DEN0, NUL, nullptr, NUL);
    conv_k<32,2048,false,true ><<<256, 512, 0, stream>>>(B1, B2, K1, 32, 0, mask, DEN0, NUL, nullptr, NUL);

    // final W conv + coords override + dist_constraint
    dc_all_kernel<<<8, 1024, 0, stream>>>(B2, x, W, mask, DEN0, XOUT, N);

    // pairwise distance matrix
    tr2dist_kernel<<<8 * 256, 256, 0, stream>>>(XOUT, out);
}